// Round 2
// baseline (480.910 us; speedup 1.0000x reference)
//
#include <hip/hip_runtime.h>
#include <stdint.h>

typedef short s16x8 __attribute__((ext_vector_type(8)));
typedef float f32x4 __attribute__((ext_vector_type(4)));

#define NPIX 65536
#define FEAT 224
#define PEND 6
#define HID  256

// fp32 -> bf16 round-to-nearest-even
__device__ __forceinline__ unsigned short f2bf(float x) {
  unsigned u = __float_as_uint(x);
  return (unsigned short)((u + 0x7FFFu + ((u >> 16) & 1u)) >> 16);
}
__device__ __forceinline__ void glds16(const void* g, void* l) {
  __builtin_amdgcn_global_load_lds(
      (const __attribute__((address_space(1))) unsigned int*)g,
      (__attribute__((address_space(3))) unsigned int*)l, 16, 0, 0);
}

// ---- converts ----
__global__ void cvtY(const float* __restrict__ Y, unsigned short* __restrict__ Yb) {
  long i = ((long)blockIdx.x * 256 + threadIdx.x) * 4;
  float4 v = *(const float4*)(Y + i);
  ushort4 o;
  o.x = f2bf(v.x); o.y = f2bf(v.y); o.z = f2bf(v.z); o.w = f2bf(v.w);
  *(ushort4*)(Yb + i) = o;
}

// W:[K][N] fp32 -> Wt:[NpadRows][K] bf16 (rows >= N zero)
__global__ void cvtWt(const float* __restrict__ W, unsigned short* __restrict__ Wt,
                      int K, int N, int NpadRows) {
  int i = blockIdx.x * 256 + threadIdx.x;
  if (i >= NpadRows * K) return;
  int n = i / K, k = i - n * K;
  unsigned short v = 0;
  if (n < N) v = f2bf(W[(long)k * N + n]);
  Wt[i] = v;
}

// ---- argmax class + counts ----
__global__ void clsk(const float* __restrict__ ab, int* __restrict__ cls,
                     int* __restrict__ counts) {
  int n = blockIdx.x * 256 + threadIdx.x;
  const float* a = ab + (long)n * PEND;
  float best = a[0]; int bi = 0;
#pragma unroll
  for (int p = 1; p < PEND; p++) { float v = a[p]; if (v > best) { best = v; bi = p; } }
  cls[n] = bi;
#pragma unroll
  for (int p = 0; p < PEND; p++) {
    unsigned long long m = __ballot(bi == p);
    if ((threadIdx.x & 63) == 0) {
      int c = __popcll(m);
      if (c) atomicAdd(&counts[p], c);
    }
  }
}

// ---- bf16 MFMA GEMM, A:[M][K] bf16 row-major, Bt:[Ncols][K] bf16 ----
// Plain variant (layers 1,2): relu + bf16 store.
__global__ __launch_bounds__(256)
void gemm_bt(const unsigned short* __restrict__ A, const unsigned short* __restrict__ Bt,
             const float* __restrict__ bias, unsigned short* __restrict__ Cout,
             int K, int Nout) {
  constexpr int BM = 128, BN = 128, BK = 32;
  __shared__ __align__(16) unsigned short As[BM * BK];
  __shared__ __align__(16) unsigned short Bs[BN * BK];
  const int tid = threadIdx.x;
  const int wid = tid >> 6;
  const int lane = tid & 63;
  const int wm = wid >> 1, wn = wid & 1;
  const long row0 = (long)blockIdx.x * BM;
  const int n0 = blockIdx.y * BN;

  const int ldr = lane >> 2;
  const int ldk = (lane & 3) * 8;
  const unsigned short* Ap = A + (row0 + wid * 32 + ldr) * (long)K + ldk;
  const unsigned short* Bp = Bt + (long)(n0 + wid * 32 + ldr) * K + ldk;
  unsigned short* AsW = As + (wid * 32) * BK;
  unsigned short* BsW = Bs + (wid * 32) * BK;

  f32x4 acc[4][4];
#pragma unroll
  for (int i = 0; i < 4; i++)
#pragma unroll
    for (int j = 0; j < 4; j++) acc[i][j] = {0.f, 0.f, 0.f, 0.f};

  const int mrow = lane & 15;
  const int quad = lane >> 4;
  const unsigned short* Abase = As + (wm * 64 + mrow) * BK + quad * 8;
  const unsigned short* Bbase = Bs + (wn * 64 + mrow) * BK + quad * 8;

  for (int k0 = 0; k0 < K; k0 += BK) {
    glds16(Ap + k0, AsW);
    glds16(Ap + k0 + 16 * (long)K, AsW + 16 * BK);
    glds16(Bp + k0, BsW);
    glds16(Bp + k0 + 16 * (long)K, BsW + 16 * BK);
    __syncthreads();
    s16x8 af[4], bfv[4];
#pragma unroll
    for (int i = 0; i < 4; i++) af[i] = *(const s16x8*)(Abase + i * 16 * BK);
#pragma unroll
    for (int j = 0; j < 4; j++) bfv[j] = *(const s16x8*)(Bbase + j * 16 * BK);
#pragma unroll
    for (int i = 0; i < 4; i++)
#pragma unroll
      for (int j = 0; j < 4; j++)
        acc[i][j] = __builtin_amdgcn_mfma_f32_16x16x32_bf16(af[i], bfv[j], acc[i][j], 0, 0, 0);
    __syncthreads();
  }

  // C/D layout: col=lane&15, row=(lane>>4)*4+reg  [m89/m91-verified]
#pragma unroll
  for (int j = 0; j < 4; j++) {
    int col = n0 + wn * 64 + j * 16 + mrow;
    float bb = bias[col];
#pragma unroll
    for (int i = 0; i < 4; i++) {
      long r0 = row0 + wm * 64 + i * 16 + quad * 4;
#pragma unroll
      for (int r = 0; r < 4; r++) {
        float v = fmaxf(acc[i][j][r] + bb, 0.f);
        Cout[(size_t)(r0 + r) * Nout + col] = f2bf(v);
      }
    }
  }
}

// Fused layer-3: logits stay in registers; epilogue computes e=exp(logit) and
// accumulates per-(class,col) {sum e, sum e*Y} via LDS, then global atomics.
__global__ __launch_bounds__(256)
void gemm3_fused(const unsigned short* __restrict__ A, const unsigned short* __restrict__ Bt,
                 const float* __restrict__ bias, const float* __restrict__ Y,
                 const int* __restrict__ cls,
                 float* __restrict__ gsum, float* __restrict__ gsumY, int K) {
  constexpr int BM = 128, BN = 128, BK = 32;
  __shared__ __align__(16) unsigned short As[BM * BK];
  __shared__ __align__(16) unsigned short Bs[BN * BK];
  __shared__ int clsS[BM];
  __shared__ float redS[BN * PEND * 2];  // [col][class][{e, e*y}] = 6 KB
  const int tid = threadIdx.x;
  const int wid = tid >> 6;
  const int lane = tid & 63;
  const int wm = wid >> 1, wn = wid & 1;
  const long row0 = (long)blockIdx.x * BM;
  const int n0 = blockIdx.y * BN;

  // init reduction LDS + stage per-row classes (covered by first K-loop barrier)
  for (int i = tid; i < BN * PEND * 2; i += 256) redS[i] = 0.f;
  if (tid < BM) clsS[tid] = cls[row0 + tid];

  const int ldr = lane >> 2;
  const int ldk = (lane & 3) * 8;
  const unsigned short* Ap = A + (row0 + wid * 32 + ldr) * (long)K + ldk;
  const unsigned short* Bp = Bt + (long)(n0 + wid * 32 + ldr) * K + ldk;
  unsigned short* AsW = As + (wid * 32) * BK;
  unsigned short* BsW = Bs + (wid * 32) * BK;

  f32x4 acc[4][4];
#pragma unroll
  for (int i = 0; i < 4; i++)
#pragma unroll
    for (int j = 0; j < 4; j++) acc[i][j] = {0.f, 0.f, 0.f, 0.f};

  const int mrow = lane & 15;
  const int quad = lane >> 4;
  const unsigned short* Abase = As + (wm * 64 + mrow) * BK + quad * 8;
  const unsigned short* Bbase = Bs + (wn * 64 + mrow) * BK + quad * 8;

  for (int k0 = 0; k0 < K; k0 += BK) {
    glds16(Ap + k0, AsW);
    glds16(Ap + k0 + 16 * (long)K, AsW + 16 * BK);
    glds16(Bp + k0, BsW);
    glds16(Bp + k0 + 16 * (long)K, BsW + 16 * BK);
    __syncthreads();
    s16x8 af[4], bfv[4];
#pragma unroll
    for (int i = 0; i < 4; i++) af[i] = *(const s16x8*)(Abase + i * 16 * BK);
#pragma unroll
    for (int j = 0; j < 4; j++) bfv[j] = *(const s16x8*)(Bbase + j * 16 * BK);
#pragma unroll
    for (int i = 0; i < 4; i++)
#pragma unroll
      for (int j = 0; j < 4; j++)
        acc[i][j] = __builtin_amdgcn_mfma_f32_16x16x32_bf16(af[i], bfv[j], acc[i][j], 0, 0, 0);
    __syncthreads();
  }

  // epilogue: exp + class-bucketed accumulation (no max-shift needed: |logit| small)
#pragma unroll
  for (int j = 0; j < 4; j++) {
    int lc = wn * 64 + j * 16 + mrow;   // local col
    int col = n0 + lc;
    bool ok = col < FEAT;
    float bb = ok ? bias[col] : 0.f;
#pragma unroll
    for (int i = 0; i < 4; i++) {
      int lr0 = wm * 64 + i * 16 + quad * 4;  // local row
#pragma unroll
      for (int r = 0; r < 4; r++) {
        if (ok) {
          float e = __expf(acc[i][j][r] + bb);
          int c = clsS[lr0 + r];
          float y = Y[(size_t)(row0 + lr0 + r) * FEAT + col];
          atomicAdd(&redS[lc * (PEND * 2) + c * 2 + 0], e);
          atomicAdd(&redS[lc * (PEND * 2) + c * 2 + 1], e * y);
        }
      }
    }
  }
  __syncthreads();
  for (int idx = tid; idx < BN * PEND * 2; idx += 256) {
    int lc = idx / (PEND * 2);
    int rem = idx - lc * (PEND * 2);
    int p = rem >> 1;
    int w = rem & 1;
    int gc = n0 + lc;
    if (gc < FEAT) {
      float v = redS[idx];
      if (v != 0.f)
        atomicAdd((w ? gsumY : gsum) + p * FEAT + gc, v);
    }
  }
}

// ---- build M and Y_hat = abundance @ M ----
__global__ __launch_bounds__(256)
void yhat(const float* __restrict__ ab, const float* __restrict__ gsum,
          const float* __restrict__ gsumY, const int* __restrict__ counts,
          float* __restrict__ out) {
  constexpr int ROWS = 64;
  __shared__ float Ms[PEND * FEAT];
  __shared__ float aS[ROWS * PEND];
  int t = threadIdx.x;
  for (int i = t; i < PEND * FEAT; i += 256) {
    int p = i / FEAT;
    float m = 0.f;
    if (counts[p] > 0) m = gsumY[i] / gsum[i];
    Ms[i] = m;
  }
  long n0 = (long)blockIdx.x * ROWS;
  const float* abb = ab + n0 * PEND;
  for (int i = t; i < ROWS * PEND; i += 256) aS[i] = abb[i];
  __syncthreads();
  if (t < FEAT) {
    for (int r = 0; r < ROWS; r++) {
      float acc = 0.f;
#pragma unroll
      for (int p = 0; p < PEND; p++) acc += aS[r * PEND + p] * Ms[p * FEAT + t];
      out[(n0 + r) * FEAT + t] = acc;
    }
  }
}

extern "C" void kernel_launch(void* const* d_in, const int* in_sizes, int n_in,
                              void* d_out, int out_size, void* d_ws, size_t ws_size,
                              hipStream_t stream) {
  const float* ab = (const float*)d_in[0];
  const float* Y  = (const float*)d_in[1];
  const float* W1 = (const float*)d_in[2];
  const float* b1 = (const float*)d_in[3];
  const float* W2 = (const float*)d_in[4];
  const float* b2 = (const float*)d_in[5];
  const float* W3 = (const float*)d_in[6];
  const float* b3 = (const float*)d_in[7];
  float* out = (float*)d_out;

  char* ws = (char*)d_ws;
  const size_t oYbf   = 0;                 // 65536*224*2 = 29,360,128
  const size_t oh1    = 29360128;          // 65536*256*2 = 33,554,432
  const size_t oh2    = 62914560;          // 33,554,432
  const size_t oW1t   = 96468992;          // 256*224*2
  const size_t oW2t   = 96583680;          // 256*256*2
  const size_t oW3t   = 96714752;          // 256*256*2 (rows>=224 zero)
  const size_t ocls   = 96845824;          // 65536*4
  const size_t osmall = 97107968;          // counts(32) + gsum(5376) + gsumY(5376)

  unsigned short* Ybf = (unsigned short*)(ws + oYbf);
  unsigned short* h1  = (unsigned short*)(ws + oh1);
  unsigned short* h2  = (unsigned short*)(ws + oh2);
  unsigned short* W1t = (unsigned short*)(ws + oW1t);
  unsigned short* W2t = (unsigned short*)(ws + oW2t);
  unsigned short* W3t = (unsigned short*)(ws + oW3t);
  int*   cls    = (int*)(ws + ocls);
  int*   counts = (int*)(ws + osmall);
  float* gsum   = (float*)(ws + osmall + 32);
  float* gsumY  = (float*)(ws + osmall + 32 + 5376);

  hipMemsetAsync(ws + osmall, 0, 32 + 2 * 5376, stream);

  cvtY<<<14336, 256, 0, stream>>>(Y, Ybf);
  cvtWt<<<224, 256, 0, stream>>>(W1, W1t, FEAT, HID, HID);
  cvtWt<<<256, 256, 0, stream>>>(W2, W2t, HID, HID, HID);
  cvtWt<<<256, 256, 0, stream>>>(W3, W3t, HID, FEAT, HID);
  clsk<<<256, 256, 0, stream>>>(ab, cls, counts);

  dim3 gg(512, 2, 1);
  gemm_bt<<<gg, 256, 0, stream>>>(Ybf, W1t, b1, h1, FEAT, HID);
  gemm_bt<<<gg, 256, 0, stream>>>(h1, W2t, b2, h2, HID, HID);
  gemm3_fused<<<gg, 256, 0, stream>>>(h2, W3t, b3, Y, cls, gsum, gsumY, HID);

  yhat<<<1024, 256, 0, stream>>>(ab, gsum, gsumY, counts, out);
}

// Round 3
// 341.073 us; speedup vs baseline: 1.4100x; 1.4100x over previous
//
#include <hip/hip_runtime.h>
#include <stdint.h>

typedef short s16x8 __attribute__((ext_vector_type(8)));
typedef float f32x4 __attribute__((ext_vector_type(4)));

#define NPIX 65536
#define FEAT 224
#define PEND 6
#define HID  256

// fp32 -> bf16 round-to-nearest-even
__device__ __forceinline__ unsigned short f2bf(float x) {
  unsigned u = __float_as_uint(x);
  return (unsigned short)((u + 0x7FFFu + ((u >> 16) & 1u)) >> 16);
}
__device__ __forceinline__ float bf2f(unsigned short b) {
  return __uint_as_float(((unsigned)b) << 16);
}
__device__ __forceinline__ void glds16(const void* g, void* l) {
  __builtin_amdgcn_global_load_lds(
      (const __attribute__((address_space(1))) unsigned int*)g,
      (__attribute__((address_space(3))) unsigned int*)l, 16, 0, 0);
}

// ---- converts ----
__global__ void cvtY(const float* __restrict__ Y, unsigned short* __restrict__ Yb) {
  long i = ((long)blockIdx.x * 256 + threadIdx.x) * 4;
  float4 v = *(const float4*)(Y + i);
  ushort4 o;
  o.x = f2bf(v.x); o.y = f2bf(v.y); o.z = f2bf(v.z); o.w = f2bf(v.w);
  *(ushort4*)(Yb + i) = o;
}

// W:[K][N] fp32 -> Wt:[NpadRows][K] bf16 (rows >= N zero)
__global__ void cvtWt(const float* __restrict__ W, unsigned short* __restrict__ Wt,
                      int K, int N, int NpadRows) {
  int i = blockIdx.x * 256 + threadIdx.x;
  if (i >= NpadRows * K) return;
  int n = i / K, k = i - n * K;
  unsigned short v = 0;
  if (n < N) v = f2bf(W[(long)k * N + n]);
  Wt[i] = v;
}

// ---- argmax class + counts ----
__global__ void clsk(const float* __restrict__ ab, int* __restrict__ cls,
                     int* __restrict__ counts) {
  int n = blockIdx.x * 256 + threadIdx.x;
  const float* a = ab + (long)n * PEND;
  float best = a[0]; int bi = 0;
#pragma unroll
  for (int p = 1; p < PEND; p++) { float v = a[p]; if (v > best) { best = v; bi = p; } }
  cls[n] = bi;
#pragma unroll
  for (int p = 0; p < PEND; p++) {
    unsigned long long m = __ballot(bi == p);
    if ((threadIdx.x & 63) == 0) {
      int c = __popcll(m);
      if (c) atomicAdd(&counts[p], c);
    }
  }
}

// ---- bf16 MFMA GEMM, A:[M][K] bf16 row-major, Bt:[Ncols][K] bf16 ----
// Writes bf16; RELU optional; cols >= Nreal dropped.
template <int RELU>
__global__ __launch_bounds__(256)
void gemm_bt(const unsigned short* __restrict__ A, const unsigned short* __restrict__ Bt,
             const float* __restrict__ bias, unsigned short* __restrict__ Cout,
             int K, int Nout, int Nreal) {
  constexpr int BM = 128, BN = 128, BK = 32;
  __shared__ __align__(16) unsigned short As[BM * BK];
  __shared__ __align__(16) unsigned short Bs[BN * BK];
  const int tid = threadIdx.x;
  const int wid = tid >> 6;
  const int lane = tid & 63;
  const int wm = wid >> 1, wn = wid & 1;
  const long row0 = (long)blockIdx.x * BM;
  const int n0 = blockIdx.y * BN;

  const int ldr = lane >> 2;
  const int ldk = (lane & 3) * 8;
  const unsigned short* Ap = A + (row0 + wid * 32 + ldr) * (long)K + ldk;
  const unsigned short* Bp = Bt + (long)(n0 + wid * 32 + ldr) * K + ldk;
  unsigned short* AsW = As + (wid * 32) * BK;
  unsigned short* BsW = Bs + (wid * 32) * BK;

  f32x4 acc[4][4];
#pragma unroll
  for (int i = 0; i < 4; i++)
#pragma unroll
    for (int j = 0; j < 4; j++) acc[i][j] = {0.f, 0.f, 0.f, 0.f};

  const int mrow = lane & 15;
  const int quad = lane >> 4;
  const unsigned short* Abase = As + (wm * 64 + mrow) * BK + quad * 8;
  const unsigned short* Bbase = Bs + (wn * 64 + mrow) * BK + quad * 8;

  for (int k0 = 0; k0 < K; k0 += BK) {
    glds16(Ap + k0, AsW);
    glds16(Ap + k0 + 16 * (long)K, AsW + 16 * BK);
    glds16(Bp + k0, BsW);
    glds16(Bp + k0 + 16 * (long)K, BsW + 16 * BK);
    __syncthreads();
    s16x8 af[4], bfv[4];
#pragma unroll
    for (int i = 0; i < 4; i++) af[i] = *(const s16x8*)(Abase + i * 16 * BK);
#pragma unroll
    for (int j = 0; j < 4; j++) bfv[j] = *(const s16x8*)(Bbase + j * 16 * BK);
#pragma unroll
    for (int i = 0; i < 4; i++)
#pragma unroll
      for (int j = 0; j < 4; j++)
        acc[i][j] = __builtin_amdgcn_mfma_f32_16x16x32_bf16(af[i], bfv[j], acc[i][j], 0, 0, 0);
    __syncthreads();
  }

  // C/D layout: col=lane&15, row=(lane>>4)*4+reg  [m89/m91-verified]
#pragma unroll
  for (int j = 0; j < 4; j++) {
    int col = n0 + wn * 64 + j * 16 + mrow;
    bool ok = col < Nreal;
    float bb = ok ? bias[col] : 0.f;
#pragma unroll
    for (int i = 0; i < 4; i++) {
      long r0 = row0 + wm * 64 + i * 16 + quad * 4;
#pragma unroll
      for (int r = 0; r < 4; r++) {
        float v = acc[i][j][r] + bb;
        if (RELU) v = fmaxf(v, 0.f);
        if (ok) Cout[(size_t)(r0 + r) * Nout + col] = f2bf(v);
      }
    }
  }
}

// ---- reducer: per-(class,feature) {sum exp(logit), sum exp*Y} ----
// 1024 blocks x 64 rows; wave wid handles rows wid,wid+4,...; lane l -> 4 features.
// Register bucketing -> barrier-sequenced LDS combine (NO LDS atomics) -> global atomics.
__global__ __launch_bounds__(256)
void reduce_k(const unsigned short* __restrict__ lg, const unsigned short* __restrict__ Ybf,
              const int* __restrict__ cls,
              float* __restrict__ gsum, float* __restrict__ gsumY) {
  __shared__ float redE[PEND * FEAT];
  __shared__ float redY[PEND * FEAT];
  const int tid = threadIdx.x;
  const int wid = tid >> 6;
  const int lane = tid & 63;
  const long n0 = (long)blockIdx.x * 64;
  const bool act = lane < 56;
  const int f0 = lane * 4;

  float accE[PEND][4], accY[PEND][4];
#pragma unroll
  for (int p = 0; p < PEND; p++)
#pragma unroll
    for (int i = 0; i < 4; i++) { accE[p][i] = 0.f; accY[p][i] = 0.f; }

  for (int r = wid; r < 64; r += 4) {
    long n = n0 + r;
    int c = cls[n];
    if (act) {
      ushort4 l4 = *(const ushort4*)(lg + n * FEAT + f0);
      ushort4 y4 = *(const ushort4*)(Ybf + n * FEAT + f0);
      float e[4], ey[4];
      e[0] = __expf(bf2f(l4.x)); e[1] = __expf(bf2f(l4.y));
      e[2] = __expf(bf2f(l4.z)); e[3] = __expf(bf2f(l4.w));
      ey[0] = e[0] * bf2f(y4.x); ey[1] = e[1] * bf2f(y4.y);
      ey[2] = e[2] * bf2f(y4.z); ey[3] = e[3] * bf2f(y4.w);
#pragma unroll
      for (int p = 0; p < PEND; p++) {
        bool m = (c == p);
#pragma unroll
        for (int i = 0; i < 4; i++) {
          accE[p][i] += m ? e[i] : 0.f;
          accY[p][i] += m ? ey[i] : 0.f;
        }
      }
    }
  }

  // cross-wave combine, one wave at a time (plain LDS r/m/w, no atomics)
  for (int w = 0; w < 4; w++) {
    if (wid == w && act) {
#pragma unroll
      for (int p = 0; p < PEND; p++) {
        float4* pe = (float4*)(redE + p * FEAT + f0);
        float4* py = (float4*)(redY + p * FEAT + f0);
        float4 ve = {accE[p][0], accE[p][1], accE[p][2], accE[p][3]};
        float4 vy = {accY[p][0], accY[p][1], accY[p][2], accY[p][3]};
        if (w == 0) { *pe = ve; *py = vy; }
        else {
          float4 oe = *pe, oy = *py;
          oe.x += ve.x; oe.y += ve.y; oe.z += ve.z; oe.w += ve.w;
          oy.x += vy.x; oy.y += vy.y; oy.z += vy.z; oy.w += vy.w;
          *pe = oe; *py = oy;
        }
      }
    }
    __syncthreads();
  }

  for (int i = tid; i < PEND * FEAT; i += 256) {
    atomicAdd(&gsum[i], redE[i]);
    atomicAdd(&gsumY[i], redY[i]);
  }
}

// ---- build M and Y_hat = abundance @ M ----
// Each lane hoists its 24 M entries to registers (avoids 8-way LDS conflicts).
__global__ __launch_bounds__(256)
void yhat(const float* __restrict__ ab, const float* __restrict__ gsum,
          const float* __restrict__ gsumY, const int* __restrict__ counts,
          float* __restrict__ out) {
  constexpr int ROWS = 64;
  __shared__ float Ms[PEND * FEAT];
  __shared__ float aS[ROWS * PEND];
  const int tid = threadIdx.x;
  for (int i = tid; i < PEND * FEAT; i += 256) {
    int p = i / FEAT;
    Ms[i] = (counts[p] > 0) ? gsumY[i] / gsum[i] : 0.f;
  }
  const long n0 = (long)blockIdx.x * ROWS;
  for (int i = tid; i < ROWS * PEND; i += 256) aS[i] = ab[n0 * PEND + i];
  __syncthreads();

  const int wid = tid >> 6;
  const int lane = tid & 63;
  if (lane >= 56) return;
  const int f0 = lane * 4;
  float4 Mr[PEND];
#pragma unroll
  for (int p = 0; p < PEND; p++) Mr[p] = *(const float4*)(Ms + p * FEAT + f0);

  for (int r = wid; r < ROWS; r += 4) {
    float a[PEND];
#pragma unroll
    for (int p = 0; p < PEND; p++) a[p] = aS[r * PEND + p];
    float4 o = {0.f, 0.f, 0.f, 0.f};
#pragma unroll
    for (int p = 0; p < PEND; p++) {
      o.x += a[p] * Mr[p].x; o.y += a[p] * Mr[p].y;
      o.z += a[p] * Mr[p].z; o.w += a[p] * Mr[p].w;
    }
    *(float4*)(out + (n0 + r) * FEAT + f0) = o;
  }
}

extern "C" void kernel_launch(void* const* d_in, const int* in_sizes, int n_in,
                              void* d_out, int out_size, void* d_ws, size_t ws_size,
                              hipStream_t stream) {
  const float* ab = (const float*)d_in[0];
  const float* Y  = (const float*)d_in[1];
  const float* W1 = (const float*)d_in[2];
  const float* b1 = (const float*)d_in[3];
  const float* W2 = (const float*)d_in[4];
  const float* b2 = (const float*)d_in[5];
  const float* W3 = (const float*)d_in[6];
  const float* b3 = (const float*)d_in[7];
  float* out = (float*)d_out;

  char* ws = (char*)d_ws;
  const size_t oYbf   = 0;                 // 65536*224*2 = 29,360,128
  const size_t oh1    = 29360128;          // 65536*256*2 = 33,554,432
  const size_t oh2    = 62914560;          // 33,554,432
  const size_t olg    = oh1;               // bf16 logits alias h1 (dead after gemm2)
  const size_t oW1t   = 96468992;          // 256*224*2
  const size_t oW2t   = 96583680;          // 256*256*2
  const size_t oW3t   = 96714752;          // 256*256*2 (rows>=224 zero)
  const size_t ocls   = 96845824;          // 65536*4
  const size_t osmall = 97107968;          // counts(32) + gsum(5376) + gsumY(5376)

  unsigned short* Ybf = (unsigned short*)(ws + oYbf);
  unsigned short* h1  = (unsigned short*)(ws + oh1);
  unsigned short* h2  = (unsigned short*)(ws + oh2);
  unsigned short* lg  = (unsigned short*)(ws + olg);
  unsigned short* W1t = (unsigned short*)(ws + oW1t);
  unsigned short* W2t = (unsigned short*)(ws + oW2t);
  unsigned short* W3t = (unsigned short*)(ws + oW3t);
  int*   cls    = (int*)(ws + ocls);
  int*   counts = (int*)(ws + osmall);
  float* gsum   = (float*)(ws + osmall + 32);
  float* gsumY  = (float*)(ws + osmall + 32 + 5376);

  hipMemsetAsync(ws + osmall, 0, 32 + 2 * 5376, stream);

  cvtY<<<14336, 256, 0, stream>>>(Y, Ybf);
  cvtWt<<<224, 256, 0, stream>>>(W1, W1t, FEAT, HID, HID);
  cvtWt<<<256, 256, 0, stream>>>(W2, W2t, HID, HID, HID);
  cvtWt<<<256, 256, 0, stream>>>(W3, W3t, HID, FEAT, HID);
  clsk<<<256, 256, 0, stream>>>(ab, cls, counts);

  dim3 gg(512, 2, 1);
  gemm_bt<1><<<gg, 256, 0, stream>>>(Ybf, W1t, b1, h1, FEAT, HID, HID);
  gemm_bt<1><<<gg, 256, 0, stream>>>(h1, W2t, b2, h2, HID, HID, HID);
  gemm_bt<0><<<gg, 256, 0, stream>>>(h2, W3t, b3, lg, HID, FEAT, FEAT);

  reduce_k<<<1024, 256, 0, stream>>>(lg, Ybf, cls, gsum, gsumY);
  yhat<<<1024, 256, 0, stream>>>(ab, gsum, gsumY, counts, out);
}

// Round 4
// 263.381 us; speedup vs baseline: 1.8259x; 1.2950x over previous
//
#include <hip/hip_runtime.h>
#include <stdint.h>

typedef short s16x8 __attribute__((ext_vector_type(8)));
typedef float f32x4 __attribute__((ext_vector_type(4)));

#define NPIX 65536
#define FEAT 224
#define PEND 6
#define HID  256

// fp32 -> bf16 round-to-nearest-even
__device__ __forceinline__ unsigned short f2bf(float x) {
  unsigned u = __float_as_uint(x);
  return (unsigned short)((u + 0x7FFFu + ((u >> 16) & 1u)) >> 16);
}
__device__ __forceinline__ float bf2f(unsigned short b) {
  return __uint_as_float(((unsigned)b) << 16);
}
__device__ __forceinline__ void glds16(const void* g, void* l) {
  __builtin_amdgcn_global_load_lds(
      (const __attribute__((address_space(1))) unsigned int*)g,
      (__attribute__((address_space(3))) unsigned int*)l, 16, 0, 0);
}

// ---- converts ----
__global__ void cvtY(const float* __restrict__ Y, unsigned short* __restrict__ Yb) {
  long i = ((long)blockIdx.x * 256 + threadIdx.x) * 4;
  float4 v = *(const float4*)(Y + i);
  ushort4 o;
  o.x = f2bf(v.x); o.y = f2bf(v.y); o.z = f2bf(v.z); o.w = f2bf(v.w);
  *(ushort4*)(Yb + i) = o;
}

// W:[K][N] fp32 -> Wt:[NpadRows][K] bf16 (rows >= N zero)
__global__ void cvtWt(const float* __restrict__ W, unsigned short* __restrict__ Wt,
                      int K, int N, int NpadRows) {
  int i = blockIdx.x * 256 + threadIdx.x;
  if (i >= NpadRows * K) return;
  int n = i / K, k = i - n * K;
  unsigned short v = 0;
  if (n < N) v = f2bf(W[(long)k * N + n]);
  Wt[i] = v;
}

// ---- bf16 MFMA GEMM, A:[M][K] bf16 row-major, Bt:[Ncols][K] bf16 ----
// Writes bf16; RELU optional; cols >= Nreal dropped.
template <int RELU>
__global__ __launch_bounds__(256)
void gemm_bt(const unsigned short* __restrict__ A, const unsigned short* __restrict__ Bt,
             const float* __restrict__ bias, unsigned short* __restrict__ Cout,
             int K, int Nout, int Nreal) {
  constexpr int BM = 128, BN = 128, BK = 32;
  __shared__ __align__(16) unsigned short As[BM * BK];
  __shared__ __align__(16) unsigned short Bs[BN * BK];
  const int tid = threadIdx.x;
  const int wid = tid >> 6;
  const int lane = tid & 63;
  const int wm = wid >> 1, wn = wid & 1;
  const long row0 = (long)blockIdx.x * BM;
  const int n0 = blockIdx.y * BN;

  const int ldr = lane >> 2;
  const int ldk = (lane & 3) * 8;
  const unsigned short* Ap = A + (row0 + wid * 32 + ldr) * (long)K + ldk;
  const unsigned short* Bp = Bt + (long)(n0 + wid * 32 + ldr) * K + ldk;
  unsigned short* AsW = As + (wid * 32) * BK;
  unsigned short* BsW = Bs + (wid * 32) * BK;

  f32x4 acc[4][4];
#pragma unroll
  for (int i = 0; i < 4; i++)
#pragma unroll
    for (int j = 0; j < 4; j++) acc[i][j] = {0.f, 0.f, 0.f, 0.f};

  const int mrow = lane & 15;
  const int quad = lane >> 4;
  const unsigned short* Abase = As + (wm * 64 + mrow) * BK + quad * 8;
  const unsigned short* Bbase = Bs + (wn * 64 + mrow) * BK + quad * 8;

  for (int k0 = 0; k0 < K; k0 += BK) {
    glds16(Ap + k0, AsW);
    glds16(Ap + k0 + 16 * (long)K, AsW + 16 * BK);
    glds16(Bp + k0, BsW);
    glds16(Bp + k0 + 16 * (long)K, BsW + 16 * BK);
    __syncthreads();
    s16x8 af[4], bfv[4];
#pragma unroll
    for (int i = 0; i < 4; i++) af[i] = *(const s16x8*)(Abase + i * 16 * BK);
#pragma unroll
    for (int j = 0; j < 4; j++) bfv[j] = *(const s16x8*)(Bbase + j * 16 * BK);
#pragma unroll
    for (int i = 0; i < 4; i++)
#pragma unroll
      for (int j = 0; j < 4; j++)
        acc[i][j] = __builtin_amdgcn_mfma_f32_16x16x32_bf16(af[i], bfv[j], acc[i][j], 0, 0, 0);
    __syncthreads();
  }

  // C/D layout: col=lane&15, row=(lane>>4)*4+reg  [m89/m91-verified]
#pragma unroll
  for (int j = 0; j < 4; j++) {
    int col = n0 + wn * 64 + j * 16 + mrow;
    bool ok = col < Nreal;
    float bb = ok ? bias[col] : 0.f;
#pragma unroll
    for (int i = 0; i < 4; i++) {
      long r0 = row0 + wm * 64 + i * 16 + quad * 4;
#pragma unroll
      for (int r = 0; r < 4; r++) {
        float v = acc[i][j][r] + bb;
        if (RELU) v = fmaxf(v, 0.f);
        if (ok) Cout[(size_t)(r0 + r) * Nout + col] = f2bf(v);
      }
    }
  }
}

// ---- reducer: per-(class,feature) {sum exp(logit), sum exp*Y} ----
// 1024 blocks x 64 rows; classes computed INLINE (no clsk kernel, no counts —
// single-cache-line global atomics serialize ~12ns/op device-wide; cost 72us in r3).
// Register bucketing -> barrier-sequenced LDS combine (NO LDS atomics; LDS atomic
// same-address contention cost 160us in r2) -> spread global atomics (42 lines: fine).
__global__ __launch_bounds__(256)
void reduce_k(const unsigned short* __restrict__ lg, const unsigned short* __restrict__ Ybf,
              const float* __restrict__ ab,
              float* __restrict__ gsum, float* __restrict__ gsumY) {
  __shared__ float redE[PEND * FEAT];
  __shared__ float redY[PEND * FEAT];
  __shared__ int clsS[64];
  const int tid = threadIdx.x;
  const int wid = tid >> 6;
  const int lane = tid & 63;
  const long n0 = (long)blockIdx.x * 64;
  const bool act = lane < 56;
  const int f0 = lane * 4;

  // inline argmax class for this block's 64 rows
  if (tid < 64) {
    const float* a = ab + (n0 + tid) * (long)PEND;
    float best = a[0]; int bi = 0;
#pragma unroll
    for (int p = 1; p < PEND; p++) { float v = a[p]; if (v > best) { best = v; bi = p; } }
    clsS[tid] = bi;
  }
  __syncthreads();

  float accE[PEND][4], accY[PEND][4];
#pragma unroll
  for (int p = 0; p < PEND; p++)
#pragma unroll
    for (int i = 0; i < 4; i++) { accE[p][i] = 0.f; accY[p][i] = 0.f; }

  for (int r = wid; r < 64; r += 4) {
    long n = n0 + r;
    int c = clsS[r];
    if (act) {
      ushort4 l4 = *(const ushort4*)(lg + n * FEAT + f0);
      ushort4 y4 = *(const ushort4*)(Ybf + n * FEAT + f0);
      float e[4], ey[4];
      e[0] = __expf(bf2f(l4.x)); e[1] = __expf(bf2f(l4.y));
      e[2] = __expf(bf2f(l4.z)); e[3] = __expf(bf2f(l4.w));
      ey[0] = e[0] * bf2f(y4.x); ey[1] = e[1] * bf2f(y4.y);
      ey[2] = e[2] * bf2f(y4.z); ey[3] = e[3] * bf2f(y4.w);
#pragma unroll
      for (int p = 0; p < PEND; p++) {
        bool m = (c == p);
#pragma unroll
        for (int i = 0; i < 4; i++) {
          accE[p][i] += m ? e[i] : 0.f;
          accY[p][i] += m ? ey[i] : 0.f;
        }
      }
    }
  }

  // cross-wave combine, one wave at a time (plain LDS r/m/w, no atomics)
  for (int w = 0; w < 4; w++) {
    if (wid == w && act) {
#pragma unroll
      for (int p = 0; p < PEND; p++) {
        float4* pe = (float4*)(redE + p * FEAT + f0);
        float4* py = (float4*)(redY + p * FEAT + f0);
        float4 ve = {accE[p][0], accE[p][1], accE[p][2], accE[p][3]};
        float4 vy = {accY[p][0], accY[p][1], accY[p][2], accY[p][3]};
        if (w == 0) { *pe = ve; *py = vy; }
        else {
          float4 oe = *pe, oy = *py;
          oe.x += ve.x; oe.y += ve.y; oe.z += ve.z; oe.w += ve.w;
          oy.x += vy.x; oy.y += vy.y; oy.z += vy.z; oy.w += vy.w;
          *pe = oe; *py = oy;
        }
      }
    }
    __syncthreads();
  }

  for (int i = tid; i < PEND * FEAT; i += 256) {
    atomicAdd(&gsum[i], redE[i]);
    atomicAdd(&gsumY[i], redY[i]);
  }
}

// ---- build M and Y_hat = abundance @ M ----
// counts[p]>0  <=>  gsum[p][f]>0 exactly (gsum = sum of exp(..)>0, or exact 0.0).
// Each lane hoists its 24 M entries to registers (avoids 8-way LDS conflicts).
__global__ __launch_bounds__(256)
void yhat(const float* __restrict__ ab, const float* __restrict__ gsum,
          const float* __restrict__ gsumY, float* __restrict__ out) {
  constexpr int ROWS = 64;
  __shared__ float Ms[PEND * FEAT];
  __shared__ float aS[ROWS * PEND];
  const int tid = threadIdx.x;
  for (int i = tid; i < PEND * FEAT; i += 256) {
    float s = gsum[i];
    Ms[i] = (s > 0.f) ? gsumY[i] / s : 0.f;
  }
  const long n0 = (long)blockIdx.x * ROWS;
  for (int i = tid; i < ROWS * PEND; i += 256) aS[i] = ab[n0 * PEND + i];
  __syncthreads();

  const int wid = tid >> 6;
  const int lane = tid & 63;
  if (lane >= 56) return;
  const int f0 = lane * 4;
  float4 Mr[PEND];
#pragma unroll
  for (int p = 0; p < PEND; p++) Mr[p] = *(const float4*)(Ms + p * FEAT + f0);

  for (int r = wid; r < ROWS; r += 4) {
    float a[PEND];
#pragma unroll
    for (int p = 0; p < PEND; p++) a[p] = aS[r * PEND + p];
    float4 o = {0.f, 0.f, 0.f, 0.f};
#pragma unroll
    for (int p = 0; p < PEND; p++) {
      o.x += a[p] * Mr[p].x; o.y += a[p] * Mr[p].y;
      o.z += a[p] * Mr[p].z; o.w += a[p] * Mr[p].w;
    }
    *(float4*)(out + (n0 + r) * FEAT + f0) = o;
  }
}

extern "C" void kernel_launch(void* const* d_in, const int* in_sizes, int n_in,
                              void* d_out, int out_size, void* d_ws, size_t ws_size,
                              hipStream_t stream) {
  const float* ab = (const float*)d_in[0];
  const float* Y  = (const float*)d_in[1];
  const float* W1 = (const float*)d_in[2];
  const float* b1 = (const float*)d_in[3];
  const float* W2 = (const float*)d_in[4];
  const float* b2 = (const float*)d_in[5];
  const float* W3 = (const float*)d_in[6];
  const float* b3 = (const float*)d_in[7];
  float* out = (float*)d_out;

  char* ws = (char*)d_ws;
  const size_t oYbf   = 0;                 // 65536*224*2 = 29,360,128
  const size_t oh1    = 29360128;          // 65536*256*2 = 33,554,432
  const size_t oh2    = 62914560;          // 33,554,432
  const size_t olg    = oh1;               // bf16 logits alias h1 (dead after gemm2)
  const size_t oW1t   = 96468992;          // 256*224*2
  const size_t oW2t   = 96583680;          // 256*256*2
  const size_t oW3t   = 96714752;          // 256*256*2 (rows>=224 zero)
  const size_t osmall = 96845824;          // gsum(5376) + gsumY(5376)

  unsigned short* Ybf = (unsigned short*)(ws + oYbf);
  unsigned short* h1  = (unsigned short*)(ws + oh1);
  unsigned short* h2  = (unsigned short*)(ws + oh2);
  unsigned short* lg  = (unsigned short*)(ws + olg);
  unsigned short* W1t = (unsigned short*)(ws + oW1t);
  unsigned short* W2t = (unsigned short*)(ws + oW2t);
  unsigned short* W3t = (unsigned short*)(ws + oW3t);
  float* gsum   = (float*)(ws + osmall);
  float* gsumY  = (float*)(ws + osmall + 5376);

  hipMemsetAsync(ws + osmall, 0, 2 * 5376, stream);

  cvtY<<<14336, 256, 0, stream>>>(Y, Ybf);
  cvtWt<<<224, 256, 0, stream>>>(W1, W1t, FEAT, HID, HID);
  cvtWt<<<256, 256, 0, stream>>>(W2, W2t, HID, HID, HID);
  cvtWt<<<256, 256, 0, stream>>>(W3, W3t, HID, FEAT, HID);

  dim3 gg(512, 2, 1);
  gemm_bt<1><<<gg, 256, 0, stream>>>(Ybf, W1t, b1, h1, FEAT, HID, HID);
  gemm_bt<1><<<gg, 256, 0, stream>>>(h1, W2t, b2, h2, HID, HID, HID);
  gemm_bt<0><<<gg, 256, 0, stream>>>(h2, W3t, b3, lg, HID, FEAT, FEAT);

  reduce_k<<<1024, 256, 0, stream>>>(lg, Ybf, ab, gsum, gsumY);
  yhat<<<1024, 256, 0, stream>>>(ab, gsum, gsumY, out);
}

// Round 5
// 263.168 us; speedup vs baseline: 1.8274x; 1.0008x over previous
//
#include <hip/hip_runtime.h>
#include <stdint.h>

typedef short s16x8 __attribute__((ext_vector_type(8)));
typedef float f32x4 __attribute__((ext_vector_type(4)));

#define NPIX 65536
#define FEAT 224
#define PEND 6
#define HID  256

// fp32 -> bf16 round-to-nearest-even
__device__ __forceinline__ unsigned short f2bf(float x) {
  unsigned u = __float_as_uint(x);
  return (unsigned short)((u + 0x7FFFu + ((u >> 16) & 1u)) >> 16);
}
__device__ __forceinline__ float bf2f(unsigned short b) {
  return __uint_as_float(((unsigned)b) << 16);
}
__device__ __forceinline__ void glds16(const void* g, void* l) {
  __builtin_amdgcn_global_load_lds(
      (const __attribute__((address_space(1))) unsigned int*)g,
      (__attribute__((address_space(3))) unsigned int*)l, 16, 0, 0);
}

// ---- converts ----
__global__ void cvtY(const float* __restrict__ Y, unsigned short* __restrict__ Yb) {
  long i = ((long)blockIdx.x * 256 + threadIdx.x) * 4;
  float4 v = *(const float4*)(Y + i);
  ushort4 o;
  o.x = f2bf(v.x); o.y = f2bf(v.y); o.z = f2bf(v.z); o.w = f2bf(v.w);
  *(ushort4*)(Yb + i) = o;
}

// W:[K][N] fp32 -> Wt:[NpadRows][K] bf16 (rows >= N zero)
__global__ void cvtWt(const float* __restrict__ W, unsigned short* __restrict__ Wt,
                      int K, int N, int NpadRows) {
  int i = blockIdx.x * 256 + threadIdx.x;
  if (i >= NpadRows * K) return;
  int n = i / K, k = i - n * K;
  unsigned short v = 0;
  if (n < N) v = f2bf(W[(long)k * N + n]);
  Wt[i] = v;
}

// ---- bf16 MFMA GEMM, A:[M][K] bf16 row-major, Bt:[Ncols][K] bf16 ----
// K-loop: 64-wide steps staged as TWO contiguous 32-panels (keeps 64B LDS row
// stride: 2-way bank alias = free, and global_load_lds lane-contiguity holds;
// a single [128][64] tile would be 16-way conflicted). Halves barrier count.
// 32-wide tail handles K%64 (K=224).
template <int RELU>
__global__ __launch_bounds__(256)
void gemm_bt(const unsigned short* __restrict__ A, const unsigned short* __restrict__ Bt,
             const float* __restrict__ bias, unsigned short* __restrict__ Cout,
             int K, int Nout, int Nreal) {
  constexpr int BM = 128, BN = 128, PK = 32;  // panel K-width
  __shared__ __align__(16) unsigned short As[2][BM * PK];
  __shared__ __align__(16) unsigned short Bs[2][BN * PK];
  const int tid = threadIdx.x;
  const int wid = tid >> 6;
  const int lane = tid & 63;
  const int wm = wid >> 1, wn = wid & 1;
  const long row0 = (long)blockIdx.x * BM;
  const int n0 = blockIdx.y * BN;

  const int ldr = lane >> 2;
  const int ldk = (lane & 3) * 8;
  const unsigned short* Ap = A + (row0 + wid * 32 + ldr) * (long)K + ldk;
  const unsigned short* Bp = Bt + (long)(n0 + wid * 32 + ldr) * K + ldk;
  unsigned short* As0W = As[0] + (wid * 32) * PK;
  unsigned short* As1W = As[1] + (wid * 32) * PK;
  unsigned short* Bs0W = Bs[0] + (wid * 32) * PK;
  unsigned short* Bs1W = Bs[1] + (wid * 32) * PK;

  f32x4 acc[4][4];
#pragma unroll
  for (int i = 0; i < 4; i++)
#pragma unroll
    for (int j = 0; j < 4; j++) acc[i][j] = {0.f, 0.f, 0.f, 0.f};

  const int mrow = lane & 15;
  const int quad = lane >> 4;
  const int aoff = (wm * 64 + mrow) * PK + quad * 8;
  const int boff = (wn * 64 + mrow) * PK + quad * 8;

  const int kfull = K & ~63;
  int k0 = 0;
  for (; k0 < kfull; k0 += 64) {
    glds16(Ap + k0, As0W);
    glds16(Ap + k0 + 16 * (long)K, As0W + 16 * PK);
    glds16(Ap + k0 + 32, As1W);
    glds16(Ap + k0 + 32 + 16 * (long)K, As1W + 16 * PK);
    glds16(Bp + k0, Bs0W);
    glds16(Bp + k0 + 16 * (long)K, Bs0W + 16 * PK);
    glds16(Bp + k0 + 32, Bs1W);
    glds16(Bp + k0 + 32 + 16 * (long)K, Bs1W + 16 * PK);
    __syncthreads();  // vmcnt(0) drain -> LDS valid
#pragma unroll
    for (int s = 0; s < 2; s++) {
      s16x8 af[4], bfv[4];
#pragma unroll
      for (int i = 0; i < 4; i++) af[i] = *(const s16x8*)(As[s] + aoff + i * 16 * PK);
#pragma unroll
      for (int j = 0; j < 4; j++) bfv[j] = *(const s16x8*)(Bs[s] + boff + j * 16 * PK);
#pragma unroll
      for (int i = 0; i < 4; i++)
#pragma unroll
        for (int j = 0; j < 4; j++)
          acc[i][j] = __builtin_amdgcn_mfma_f32_16x16x32_bf16(af[i], bfv[j], acc[i][j], 0, 0, 0);
    }
    __syncthreads();  // protect LDS before next stage
  }
  if (k0 < K) {  // 32-wide tail
    glds16(Ap + k0, As0W);
    glds16(Ap + k0 + 16 * (long)K, As0W + 16 * PK);
    glds16(Bp + k0, Bs0W);
    glds16(Bp + k0 + 16 * (long)K, Bs0W + 16 * PK);
    __syncthreads();
    s16x8 af[4], bfv[4];
#pragma unroll
    for (int i = 0; i < 4; i++) af[i] = *(const s16x8*)(As[0] + aoff + i * 16 * PK);
#pragma unroll
    for (int j = 0; j < 4; j++) bfv[j] = *(const s16x8*)(Bs[0] + boff + j * 16 * PK);
#pragma unroll
    for (int i = 0; i < 4; i++)
#pragma unroll
      for (int j = 0; j < 4; j++)
        acc[i][j] = __builtin_amdgcn_mfma_f32_16x16x32_bf16(af[i], bfv[j], acc[i][j], 0, 0, 0);
  }

  // C/D layout: col=lane&15, row=(lane>>4)*4+reg  [m89/m91-verified]
#pragma unroll
  for (int j = 0; j < 4; j++) {
    int col = n0 + wn * 64 + j * 16 + mrow;
    bool ok = col < Nreal;
    float bb = ok ? bias[col] : 0.f;
#pragma unroll
    for (int i = 0; i < 4; i++) {
      long r0 = row0 + wm * 64 + i * 16 + quad * 4;
#pragma unroll
      for (int r = 0; r < 4; r++) {
        float v = acc[i][j][r] + bb;
        if (RELU) v = fmaxf(v, 0.f);
        if (ok) Cout[(size_t)(r0 + r) * Nout + col] = f2bf(v);
      }
    }
  }
}

// ---- reducer: per-(class,feature) {sum exp(logit), sum exp*Y} ----
// Class c is WAVE-UNIFORM per row -> readfirstlane + scalar switch picks the
// accumulator pair: 8 VALU adds/row instead of 6-way masked accumulate (~48).
// No LDS atomics (r2: 160us loss), no single-line global atomics (r3: 72us loss).
__global__ __launch_bounds__(256)
void reduce_k(const unsigned short* __restrict__ lg, const unsigned short* __restrict__ Ybf,
              const float* __restrict__ ab,
              float* __restrict__ gsum, float* __restrict__ gsumY) {
  __shared__ float redE[PEND * FEAT];
  __shared__ float redY[PEND * FEAT];
  __shared__ int clsS[64];
  const int tid = threadIdx.x;
  const int wid = tid >> 6;
  const int lane = tid & 63;
  const long n0 = (long)blockIdx.x * 64;
  const bool act = lane < 56;
  const int f0 = lane * 4;

  // inline argmax class for this block's 64 rows
  if (tid < 64) {
    const float* a = ab + (n0 + tid) * (long)PEND;
    float best = a[0]; int bi = 0;
#pragma unroll
    for (int p = 1; p < PEND; p++) { float v = a[p]; if (v > best) { best = v; bi = p; } }
    clsS[tid] = bi;
  }
  __syncthreads();

  float accE[PEND][4], accY[PEND][4];
#pragma unroll
  for (int p = 0; p < PEND; p++)
#pragma unroll
    for (int i = 0; i < 4; i++) { accE[p][i] = 0.f; accY[p][i] = 0.f; }

  for (int r = wid; r < 64; r += 4) {
    long n = n0 + r;
    if (act) {
      int c = __builtin_amdgcn_readfirstlane(clsS[r]);
      ushort4 l4 = *(const ushort4*)(lg + n * FEAT + f0);
      ushort4 y4 = *(const ushort4*)(Ybf + n * FEAT + f0);
      float e[4], ey[4];
      e[0] = __expf(bf2f(l4.x)); e[1] = __expf(bf2f(l4.y));
      e[2] = __expf(bf2f(l4.z)); e[3] = __expf(bf2f(l4.w));
      ey[0] = e[0] * bf2f(y4.x); ey[1] = e[1] * bf2f(y4.y);
      ey[2] = e[2] * bf2f(y4.z); ey[3] = e[3] * bf2f(y4.w);
#define RK_CASE(P)                                                     \
      case P:                                                          \
        _Pragma("unroll")                                              \
        for (int i = 0; i < 4; i++) { accE[P][i] += e[i]; accY[P][i] += ey[i]; } \
        break;
      switch (c) {
        RK_CASE(0) RK_CASE(1) RK_CASE(2) RK_CASE(3) RK_CASE(4) RK_CASE(5)
      }
#undef RK_CASE
    }
  }

  // cross-wave combine, one wave at a time (plain LDS r/m/w, no atomics)
  for (int w = 0; w < 4; w++) {
    if (wid == w && act) {
#pragma unroll
      for (int p = 0; p < PEND; p++) {
        float4* pe = (float4*)(redE + p * FEAT + f0);
        float4* py = (float4*)(redY + p * FEAT + f0);
        float4 ve = {accE[p][0], accE[p][1], accE[p][2], accE[p][3]};
        float4 vy = {accY[p][0], accY[p][1], accY[p][2], accY[p][3]};
        if (w == 0) { *pe = ve; *py = vy; }
        else {
          float4 oe = *pe, oy = *py;
          oe.x += ve.x; oe.y += ve.y; oe.z += ve.z; oe.w += ve.w;
          oy.x += vy.x; oy.y += vy.y; oy.z += vy.z; oy.w += vy.w;
          *pe = oe; *py = oy;
        }
      }
    }
    __syncthreads();
  }

  for (int i = tid; i < PEND * FEAT; i += 256) {
    atomicAdd(&gsum[i], redE[i]);
    atomicAdd(&gsumY[i], redY[i]);
  }
}

// ---- build M and Y_hat = abundance @ M ----
// counts[p]>0  <=>  gsum[p][f]>0 exactly (gsum = sum of exp(..)>0, or exact 0.0).
// Each lane hoists its 24 M entries to registers (avoids 8-way LDS conflicts).
__global__ __launch_bounds__(256)
void yhat(const float* __restrict__ ab, const float* __restrict__ gsum,
          const float* __restrict__ gsumY, float* __restrict__ out) {
  constexpr int ROWS = 64;
  __shared__ float Ms[PEND * FEAT];
  __shared__ float aS[ROWS * PEND];
  const int tid = threadIdx.x;
  for (int i = tid; i < PEND * FEAT; i += 256) {
    float s = gsum[i];
    Ms[i] = (s > 0.f) ? gsumY[i] / s : 0.f;
  }
  const long n0 = (long)blockIdx.x * ROWS;
  for (int i = tid; i < ROWS * PEND; i += 256) aS[i] = ab[n0 * PEND + i];
  __syncthreads();

  const int wid = tid >> 6;
  const int lane = tid & 63;
  if (lane >= 56) return;
  const int f0 = lane * 4;
  float4 Mr[PEND];
#pragma unroll
  for (int p = 0; p < PEND; p++) Mr[p] = *(const float4*)(Ms + p * FEAT + f0);

  for (int r = wid; r < ROWS; r += 4) {
    float a[PEND];
#pragma unroll
    for (int p = 0; p < PEND; p++) a[p] = aS[r * PEND + p];
    float4 o = {0.f, 0.f, 0.f, 0.f};
#pragma unroll
    for (int p = 0; p < PEND; p++) {
      o.x += a[p] * Mr[p].x; o.y += a[p] * Mr[p].y;
      o.z += a[p] * Mr[p].z; o.w += a[p] * Mr[p].w;
    }
    *(float4*)(out + (n0 + r) * FEAT + f0) = o;
  }
}

extern "C" void kernel_launch(void* const* d_in, const int* in_sizes, int n_in,
                              void* d_out, int out_size, void* d_ws, size_t ws_size,
                              hipStream_t stream) {
  const float* ab = (const float*)d_in[0];
  const float* Y  = (const float*)d_in[1];
  const float* W1 = (const float*)d_in[2];
  const float* b1 = (const float*)d_in[3];
  const float* W2 = (const float*)d_in[4];
  const float* b2 = (const float*)d_in[5];
  const float* W3 = (const float*)d_in[6];
  const float* b3 = (const float*)d_in[7];
  float* out = (float*)d_out;

  char* ws = (char*)d_ws;
  const size_t oYbf   = 0;                 // 65536*224*2 = 29,360,128
  const size_t oh1    = 29360128;          // 65536*256*2 = 33,554,432
  const size_t oh2    = 62914560;          // 33,554,432
  const size_t olg    = oh1;               // bf16 logits alias h1 (dead after gemm2)
  const size_t oW1t   = 96468992;          // 256*224*2
  const size_t oW2t   = 96583680;          // 256*256*2
  const size_t oW3t   = 96714752;          // 256*256*2 (rows>=224 zero)
  const size_t osmall = 96845824;          // gsum(5376) + gsumY(5376)

  unsigned short* Ybf = (unsigned short*)(ws + oYbf);
  unsigned short* h1  = (unsigned short*)(ws + oh1);
  unsigned short* h2  = (unsigned short*)(ws + oh2);
  unsigned short* lg  = (unsigned short*)(ws + olg);
  unsigned short* W1t = (unsigned short*)(ws + oW1t);
  unsigned short* W2t = (unsigned short*)(ws + oW2t);
  unsigned short* W3t = (unsigned short*)(ws + oW3t);
  float* gsum   = (float*)(ws + osmall);
  float* gsumY  = (float*)(ws + osmall + 5376);

  hipMemsetAsync(ws + osmall, 0, 2 * 5376, stream);

  cvtY<<<14336, 256, 0, stream>>>(Y, Ybf);
  cvtWt<<<224, 256, 0, stream>>>(W1, W1t, FEAT, HID, HID);
  cvtWt<<<256, 256, 0, stream>>>(W2, W2t, HID, HID, HID);
  cvtWt<<<256, 256, 0, stream>>>(W3, W3t, HID, FEAT, HID);

  dim3 gg(512, 2, 1);
  gemm_bt<1><<<gg, 256, 0, stream>>>(Ybf, W1t, b1, h1, FEAT, HID, HID);
  gemm_bt<1><<<gg, 256, 0, stream>>>(h1, W2t, b2, h2, HID, HID, HID);
  gemm_bt<0><<<gg, 256, 0, stream>>>(h2, W3t, b3, lg, HID, FEAT, FEAT);

  reduce_k<<<1024, 256, 0, stream>>>(lg, Ybf, ab, gsum, gsumY);
  yhat<<<1024, 256, 0, stream>>>(ab, gsum, gsumY, out);
}

// Round 6
// 211.449 us; speedup vs baseline: 2.2744x; 1.2446x over previous
//
#include <hip/hip_runtime.h>
#include <stdint.h>

typedef short s16x8 __attribute__((ext_vector_type(8)));
typedef short s16x4 __attribute__((ext_vector_type(4)));
typedef float f32x4 __attribute__((ext_vector_type(4)));

#define NPIX 65536
#define FEAT 224
#define PEND 6
#define HID  256

// fp32 -> bf16 round-to-nearest-even
__device__ __forceinline__ unsigned short f2bf(float x) {
  unsigned u = __float_as_uint(x);
  return (unsigned short)((u + 0x7FFFu + ((u >> 16) & 1u)) >> 16);
}
__device__ __forceinline__ float bf2f(unsigned short b) {
  return __uint_as_float(((unsigned)b) << 16);
}
__device__ __forceinline__ void glds16(const void* g, void* l) {
  __builtin_amdgcn_global_load_lds(
      (const __attribute__((address_space(1))) unsigned int*)g,
      (__attribute__((address_space(3))) unsigned int*)l, 16, 0, 0);
}

// ---- one-shot weight transpose+convert: W[K][N] fp32 -> Wt[N(pad)][K] bf16 ----
__global__ void cvtW_all(const float* __restrict__ W1, const float* __restrict__ W2,
                         const float* __restrict__ W3,
                         unsigned short* __restrict__ W1t, unsigned short* __restrict__ W2t,
                         unsigned short* __restrict__ W3t) {
  int i = blockIdx.x * 256 + threadIdx.x;
  if (i < 57344) {                       // W1t: [256][224] from W1[224][256]
    int n = i / 224, k = i - n * 224;
    W1t[i] = f2bf(W1[k * 256 + n]);
  } else if (i < 122880) {               // W2t: [256][256] from W2[256][256]
    int i2 = i - 57344;
    int n = i2 >> 8, k = i2 & 255;
    W2t[i2] = f2bf(W2[k * 256 + n]);
  } else if (i < 188416) {               // W3t: [256(pad)][256] from W3[256][224]
    int i3 = i - 122880;
    int n = i3 >> 8, k = i3 & 255;
    W3t[i3] = (n < FEAT) ? f2bf(W3[k * FEAT + n]) : (unsigned short)0;
  }
}

// ---- fused: Y -> relu(YW1+b1) -> relu(hW2+b2) -> logits -> e=exp -> per-class sums ----
// 1024 blocks x 64 pixels. All intermediates in LDS (exactly 64 KB static -> 2 blocks/CU).
// h/e tile: [64][264] bf16 (pad 8 shorts keeps ds_read_b128 <=2-way bank alias = free,
// m136). Weights staged per 32-K panel via glds16 (L2-hot, 360 KB total).
// Reduce: wave-uniform class scalar-switch (r5), sequenced LDS combine (no LDS atomics
// -- r2: -160us), spread global atomics (1024/addr -- r1-proven fine).
__global__ __launch_bounds__(256, 2)
void fused_mlp(const float* __restrict__ Y,
               const unsigned short* __restrict__ W1t,
               const unsigned short* __restrict__ W2t,
               const unsigned short* __restrict__ W3t,
               const float* __restrict__ b1, const float* __restrict__ b2,
               const float* __restrict__ b3, const float* __restrict__ ab,
               float* __restrict__ gsum, float* __restrict__ gsumY) {
  constexpr int HPAD = 264;  // h/e row stride (shorts)
  constexpr int APAD = 36;   // layer-1 A-stage row stride (shorts, 8B-aligned rows)
  __shared__ __align__(16) unsigned short hS[64 * HPAD];  // 33792 B
  __shared__ __align__(16) unsigned short As[64 * APAD];  //  4608 B
  __shared__ __align__(16) unsigned short Bs[256 * 32];   // 16384 B
  __shared__ __align__(16) float redE[PEND * FEAT];       //  5376 B
  __shared__ __align__(16) float redY[PEND * FEAT];       //  5376 B  (total 65536)
  const int tid = threadIdx.x;
  const int wid = tid >> 6;
  const int lane = tid & 63;
  const int wm = wid >> 1, wn = wid & 1;
  const int mrow = lane & 15, quad = lane >> 4;
  const long row0 = (long)blockIdx.x * 64;

  // B staging: wave wid covers Wt rows [wid*64, wid*64+64), 4 glds16 calls
  const int brow = lane >> 2;
  const int bk8 = (lane & 3) * 8;
  unsigned short* BsW = Bs + (wid * 64) * 32;
  // layer-1 A staging: thread -> (row = tid>>2, 8-short chunk = tid&3)
  const int arow = tid >> 2, aqtr = tid & 3;

  f32x4 acc[2][8];

  // ================= layer 1: h1 = relu(Y @ W1 + b1), K=224 =================
#pragma unroll
  for (int i = 0; i < 2; i++)
#pragma unroll
    for (int j = 0; j < 8; j++) acc[i][j] = {0.f, 0.f, 0.f, 0.f};

  for (int p = 0; p < 7; p++) {
    const int k0 = p * 32;
    {  // stage A: fp32 -> bf16 -> LDS
      const float* src = Y + (row0 + arow) * FEAT + k0 + aqtr * 8;
      float4 v0 = *(const float4*)src;
      float4 v1 = *(const float4*)(src + 4);
      s16x4 lo = {(short)f2bf(v0.x), (short)f2bf(v0.y), (short)f2bf(v0.z), (short)f2bf(v0.w)};
      s16x4 hi = {(short)f2bf(v1.x), (short)f2bf(v1.y), (short)f2bf(v1.z), (short)f2bf(v1.w)};
      *(s16x4*)(As + arow * APAD + aqtr * 8) = lo;
      *(s16x4*)(As + arow * APAD + aqtr * 8 + 4) = hi;
    }
#pragma unroll
    for (int c = 0; c < 4; c++)
      glds16(W1t + (size_t)(wid * 64 + c * 16 + brow) * FEAT + k0 + bk8, BsW + c * 16 * 32);
    __syncthreads();
    s16x8 af[2], bfv[8];
#pragma unroll
    for (int i = 0; i < 2; i++) {
      const unsigned short* pa = As + (wm * 32 + i * 16 + mrow) * APAD + quad * 8;
      s16x4 lo = *(const s16x4*)pa, hi = *(const s16x4*)(pa + 4);
      af[i] = __builtin_shufflevector(lo, hi, 0, 1, 2, 3, 4, 5, 6, 7);
    }
#pragma unroll
    for (int j = 0; j < 8; j++)
      bfv[j] = *(const s16x8*)(Bs + (wn * 128 + j * 16 + mrow) * 32 + quad * 8);
#pragma unroll
    for (int i = 0; i < 2; i++)
#pragma unroll
      for (int j = 0; j < 8; j++)
        acc[i][j] = __builtin_amdgcn_mfma_f32_16x16x32_bf16(af[i], bfv[j], acc[i][j], 0, 0, 0);
    __syncthreads();
  }
  // h1 epilogue -> hS (C/D: col=lane&15, row=quad*4+reg; m89/m91-verified)
#pragma unroll
  for (int j = 0; j < 8; j++) {
    int col = wn * 128 + j * 16 + mrow;
    float bb = b1[col];
#pragma unroll
    for (int i = 0; i < 2; i++) {
      int r0 = wm * 32 + i * 16 + quad * 4;
#pragma unroll
      for (int r = 0; r < 4; r++)
        hS[(r0 + r) * HPAD + col] = f2bf(fmaxf(acc[i][j][r] + bb, 0.f));
    }
  }
  __syncthreads();

  // ================= layer 2: h2 = relu(h1 @ W2 + b2), K=256 =================
#pragma unroll
  for (int i = 0; i < 2; i++)
#pragma unroll
    for (int j = 0; j < 8; j++) acc[i][j] = {0.f, 0.f, 0.f, 0.f};
  for (int p = 0; p < 8; p++) {
    const int k0 = p * 32;
#pragma unroll
    for (int c = 0; c < 4; c++)
      glds16(W2t + (size_t)(wid * 64 + c * 16 + brow) * HID + k0 + bk8, BsW + c * 16 * 32);
    __syncthreads();
    s16x8 af[2], bfv[8];
#pragma unroll
    for (int i = 0; i < 2; i++)
      af[i] = *(const s16x8*)(hS + (wm * 32 + i * 16 + mrow) * HPAD + k0 + quad * 8);
#pragma unroll
    for (int j = 0; j < 8; j++)
      bfv[j] = *(const s16x8*)(Bs + (wn * 128 + j * 16 + mrow) * 32 + quad * 8);
#pragma unroll
    for (int i = 0; i < 2; i++)
#pragma unroll
      for (int j = 0; j < 8; j++)
        acc[i][j] = __builtin_amdgcn_mfma_f32_16x16x32_bf16(af[i], bfv[j], acc[i][j], 0, 0, 0);
    __syncthreads();
  }
  // h2 epilogue -> hS (overwrite h1; all waves past last K-read via loop-end barrier)
#pragma unroll
  for (int j = 0; j < 8; j++) {
    int col = wn * 128 + j * 16 + mrow;
    float bb = b2[col];
#pragma unroll
    for (int i = 0; i < 2; i++) {
      int r0 = wm * 32 + i * 16 + quad * 4;
#pragma unroll
      for (int r = 0; r < 4; r++)
        hS[(r0 + r) * HPAD + col] = f2bf(fmaxf(acc[i][j][r] + bb, 0.f));
    }
  }
  __syncthreads();

  // ========== layer 3: logits = h2 @ W3 + b3 (fp32 in regs), K=256 ==========
#pragma unroll
  for (int i = 0; i < 2; i++)
#pragma unroll
    for (int j = 0; j < 8; j++) acc[i][j] = {0.f, 0.f, 0.f, 0.f};
  for (int p = 0; p < 8; p++) {
    const int k0 = p * 32;
#pragma unroll
    for (int c = 0; c < 4; c++)
      glds16(W3t + (size_t)(wid * 64 + c * 16 + brow) * HID + k0 + bk8, BsW + c * 16 * 32);
    __syncthreads();
    s16x8 af[2], bfv[8];
#pragma unroll
    for (int i = 0; i < 2; i++)
      af[i] = *(const s16x8*)(hS + (wm * 32 + i * 16 + mrow) * HPAD + k0 + quad * 8);
#pragma unroll
    for (int j = 0; j < 8; j++)
      bfv[j] = *(const s16x8*)(Bs + (wn * 128 + j * 16 + mrow) * 32 + quad * 8);
#pragma unroll
    for (int i = 0; i < 2; i++)
#pragma unroll
      for (int j = 0; j < 8; j++)
        acc[i][j] = __builtin_amdgcn_mfma_f32_16x16x32_bf16(af[i], bfv[j], acc[i][j], 0, 0, 0);
    __syncthreads();
  }
  // e = exp(logit) -> hS bf16 (no max-shift: |logit| small; r1-validated)
#pragma unroll
  for (int j = 0; j < 8; j++) {
    int col = wn * 128 + j * 16 + mrow;
    if (col < FEAT) {
      float bb = b3[col];
#pragma unroll
      for (int i = 0; i < 2; i++) {
        int r0 = wm * 32 + i * 16 + quad * 4;
#pragma unroll
        for (int r = 0; r < 4; r++)
          hS[(r0 + r) * HPAD + col] = f2bf(__expf(acc[i][j][r] + bb));
      }
    }
  }
  __syncthreads();

  // ================= reduce: per-(class,feature) {sum e, sum e*Y} =================
  const bool act = lane < 56;
  const int f0 = lane * 4;
  float accE[PEND][4], accY[PEND][4];
#pragma unroll
  for (int p = 0; p < PEND; p++)
#pragma unroll
    for (int i = 0; i < 4; i++) { accE[p][i] = 0.f; accY[p][i] = 0.f; }

  for (int r = wid; r < 64; r += 4) {
    // wave-uniform argmax class (same addr across lanes -> broadcast loads, L2-hot)
    const float* a = ab + (row0 + r) * PEND;
    float best = a[0]; int c = 0;
#pragma unroll
    for (int p = 1; p < PEND; p++) { float v = a[p]; if (v > best) { best = v; c = p; } }
    c = __builtin_amdgcn_readfirstlane(c);
    if (act) {
      ushort4 e4 = *(const ushort4*)(hS + r * HPAD + f0);
      float4 y4 = *(const float4*)(Y + (row0 + r) * FEAT + f0);
      float e[4] = {bf2f(e4.x), bf2f(e4.y), bf2f(e4.z), bf2f(e4.w)};
      float ey[4] = {e[0] * y4.x, e[1] * y4.y, e[2] * y4.z, e[3] * y4.w};
#define RK_CASE(P)                                                               \
      case P:                                                                    \
        _Pragma("unroll")                                                        \
        for (int i = 0; i < 4; i++) { accE[P][i] += e[i]; accY[P][i] += ey[i]; } \
        break;
      switch (c) {
        RK_CASE(0) RK_CASE(1) RK_CASE(2) RK_CASE(3) RK_CASE(4) RK_CASE(5)
      }
#undef RK_CASE
    }
  }

  // cross-wave combine, one wave at a time (plain LDS r/m/w, no atomics)
  for (int w = 0; w < 4; w++) {
    if (wid == w && act) {
#pragma unroll
      for (int p = 0; p < PEND; p++) {
        float4* pe = (float4*)(redE + p * FEAT + f0);
        float4* py = (float4*)(redY + p * FEAT + f0);
        float4 ve = {accE[p][0], accE[p][1], accE[p][2], accE[p][3]};
        float4 vy = {accY[p][0], accY[p][1], accY[p][2], accY[p][3]};
        if (w == 0) { *pe = ve; *py = vy; }
        else {
          float4 oe = *pe, oy = *py;
          oe.x += ve.x; oe.y += ve.y; oe.z += ve.z; oe.w += ve.w;
          oy.x += vy.x; oy.y += vy.y; oy.z += vy.z; oy.w += vy.w;
          *pe = oe; *py = oy;
        }
      }
    }
    __syncthreads();
  }

  for (int i = tid; i < PEND * FEAT; i += 256) {
    atomicAdd(&gsum[i], redE[i]);
    atomicAdd(&gsumY[i], redY[i]);
  }
}

// ---- build M and Y_hat = abundance @ M ----
// counts[p]>0 <=> gsum[p][f]>0 exactly. M entries hoisted to registers.
__global__ __launch_bounds__(256)
void yhat(const float* __restrict__ ab, const float* __restrict__ gsum,
          const float* __restrict__ gsumY, float* __restrict__ out) {
  constexpr int ROWS = 64;
  __shared__ float Ms[PEND * FEAT];
  __shared__ float aS[ROWS * PEND];
  const int tid = threadIdx.x;
  for (int i = tid; i < PEND * FEAT; i += 256) {
    float s = gsum[i];
    Ms[i] = (s > 0.f) ? gsumY[i] / s : 0.f;
  }
  const long n0 = (long)blockIdx.x * ROWS;
  for (int i = tid; i < ROWS * PEND; i += 256) aS[i] = ab[n0 * PEND + i];
  __syncthreads();

  const int wid = tid >> 6;
  const int lane = tid & 63;
  if (lane >= 56) return;
  const int f0 = lane * 4;
  float4 Mr[PEND];
#pragma unroll
  for (int p = 0; p < PEND; p++) Mr[p] = *(const float4*)(Ms + p * FEAT + f0);

  for (int r = wid; r < ROWS; r += 4) {
    float a[PEND];
#pragma unroll
    for (int p = 0; p < PEND; p++) a[p] = aS[r * PEND + p];
    float4 o = {0.f, 0.f, 0.f, 0.f};
#pragma unroll
    for (int p = 0; p < PEND; p++) {
      o.x += a[p] * Mr[p].x; o.y += a[p] * Mr[p].y;
      o.z += a[p] * Mr[p].z; o.w += a[p] * Mr[p].w;
    }
    *(float4*)(out + (n0 + r) * FEAT + f0) = o;
  }
}

extern "C" void kernel_launch(void* const* d_in, const int* in_sizes, int n_in,
                              void* d_out, int out_size, void* d_ws, size_t ws_size,
                              hipStream_t stream) {
  const float* ab = (const float*)d_in[0];
  const float* Y  = (const float*)d_in[1];
  const float* W1 = (const float*)d_in[2];
  const float* b1 = (const float*)d_in[3];
  const float* W2 = (const float*)d_in[4];
  const float* b2 = (const float*)d_in[5];
  const float* W3 = (const float*)d_in[6];
  const float* b3 = (const float*)d_in[7];
  float* out = (float*)d_out;

  char* ws = (char*)d_ws;
  const size_t oW1t  = 0;        // 256*224*2 = 114,688
  const size_t oW2t  = 114688;   // 256*256*2 = 131,072
  const size_t oW3t  = 245760;   // 256*256*2 = 131,072 (rows>=224 zero)
  const size_t osum  = 376832;   // gsum 5376 + gsumY 5376

  unsigned short* W1t = (unsigned short*)(ws + oW1t);
  unsigned short* W2t = (unsigned short*)(ws + oW2t);
  unsigned short* W3t = (unsigned short*)(ws + oW3t);
  float* gsum  = (float*)(ws + osum);
  float* gsumY = (float*)(ws + osum + 5376);

  hipMemsetAsync(ws + osum, 0, 2 * 5376, stream);
  cvtW_all<<<736, 256, 0, stream>>>(W1, W2, W3, W1t, W2t, W3t);
  fused_mlp<<<1024, 256, 0, stream>>>(Y, W1t, W2t, W3t, b1, b2, b3, ab, gsum, gsumY);
  yhat<<<1024, 256, 0, stream>>>(ab, gsum, gsumY, out);
}